// Round 6
// baseline (370.630 us; speedup 1.0000x reference)
//
#include <hip/hip_runtime.h>
#include <math.h>

#define B_  4
#define S_  2048
#define DM_ 1024
#define H_  16
#define HD_ 64

typedef float f32x4 __attribute__((ext_vector_type(4)));
typedef short bf16x8 __attribute__((ext_vector_type(8)));

#define MFMA16(a, b, c) __builtin_amdgcn_mfma_f32_16x16x32_bf16((a), (b), (c), 0, 0, 0)

static __device__ __forceinline__ unsigned short f2bf(float f) {
    union { float f; unsigned int i; } c; c.f = f;
    unsigned int u = c.i;
    return (unsigned short)((u + 0x7fffu + ((u >> 16) & 1u)) >> 16);
}
static __device__ __forceinline__ unsigned int f2u(float f) {
    union { float f; unsigned int u; } c; c.f = f; return c.u;
}

// async global->LDS, 16B per lane. lds ptr must be wave-uniform; lane i lands at l + i*16B.
static __device__ __forceinline__ void async16(const void* g, void* l) {
    __builtin_amdgcn_global_load_lds(
        (__attribute__((address_space(1))) void*)(void*)g,
        (__attribute__((address_space(3))) void*)l, 16, 0, 0);
}

// ---------------------------------------------------------------------------
// fp32 -> bf16 cast for Q,K,V (z picks the tensor), 8 elems/thread
// ---------------------------------------------------------------------------
__global__ __launch_bounds__(256) void cast3_bf16(
    const float* __restrict__ q, const float* __restrict__ k,
    const float* __restrict__ v,
    unsigned short* __restrict__ qo, unsigned short* __restrict__ ko,
    unsigned short* __restrict__ vo) {
    const int z = blockIdx.z;
    const float* in = z == 0 ? q : (z == 1 ? k : v);
    unsigned short* out = z == 0 ? qo : (z == 1 ? ko : vo);
    int idx = (blockIdx.x * 256 + threadIdx.x) * 8;
    float4 a = *(const float4*)(in + idx);
    float4 b = *(const float4*)(in + idx + 4);
    *(ushort4*)(out + idx)     = make_ushort4(f2bf(a.x), f2bf(a.y), f2bf(a.z), f2bf(a.w));
    *(ushort4*)(out + idx + 4) = make_ushort4(f2bf(b.x), f2bf(b.y), f2bf(b.z), f2bf(b.w));
}

// ---------------------------------------------------------------------------
// W fp32 [K][N] -> Wt bf16 [N][K]  (64x64 tiles via LDS); z picks the weight.
// ---------------------------------------------------------------------------
__global__ __launch_bounds__(256) void wcast4_t(
    const float* __restrict__ w0, const float* __restrict__ w1,
    const float* __restrict__ w2, const float* __restrict__ w3,
    unsigned short* __restrict__ o0, unsigned short* __restrict__ o1,
    unsigned short* __restrict__ o2, unsigned short* __restrict__ o3) {
    __shared__ float tile[64][65];
    const int z = blockIdx.z;
    const float* W = z == 0 ? w0 : (z == 1 ? w1 : (z == 2 ? w2 : w3));
    unsigned short* Wt = z == 0 ? o0 : (z == 1 ? o1 : (z == 2 ? o2 : o3));
    const int t = threadIdx.x;
    const int k0 = blockIdx.y * 64, n0 = blockIdx.x * 64;
    const int r = t >> 4, c4 = (t & 15) * 4;
    #pragma unroll
    for (int s = 0; s < 4; ++s) {
        float4 f = *(const float4*)(W + (size_t)(k0 + s * 16 + r) * DM_ + n0 + c4);
        tile[s * 16 + r][c4 + 0] = f.x; tile[s * 16 + r][c4 + 1] = f.y;
        tile[s * 16 + r][c4 + 2] = f.z; tile[s * 16 + r][c4 + 3] = f.w;
    }
    __syncthreads();
    #pragma unroll
    for (int s = 0; s < 4; ++s) {
        int n = s * 16 + r;
        ushort4 o = make_ushort4(f2bf(tile[c4 + 0][n]), f2bf(tile[c4 + 1][n]),
                                 f2bf(tile[c4 + 2][n]), f2bf(tile[c4 + 3][n]));
        *(ushort4*)(Wt + (size_t)(n0 + n) * DM_ + k0 + c4) = o;
    }
}

// ---------------------------------------------------------------------------
// MFMA GEMM core: C[M=8192][N=1024] = A_bf16[M][K=1024] @ Wt_bf16[N][K]^T + bias
// 128x128 tile, BK=64 (32 MFMA per barrier-pair), 256 thr / 4 waves.
// LDS rows are 64 bf16 = 128 B; 16B chunks XOR-swizzled by (row&7) so
// fragment ds_read_b128 are conflict-free (global_load_lds forbids padding).
// mode 0: bf16 out [B,H,S,64]; mode 1: bf16 out [B,H,64,S]; mode 2: fp32 row-major
// ---------------------------------------------------------------------------
static __device__ __forceinline__ void gemm_body(
    const unsigned short* __restrict__ A,
    const unsigned short* __restrict__ Wt,
    const float* __restrict__ bias,
    void* __restrict__ outp, int mode,
    unsigned short* As, unsigned short* Bs)
{
    const int t = threadIdx.x;
    const int w = t >> 6, l = t & 63;
    const int quad = l >> 4, l16 = l & 15;
    const int wr = w >> 1, wc = w & 1;
    const int m0 = blockIdx.y * 128, n0 = blockIdx.x * 128;

    const int srow8 = l >> 3;               // 0..7, == row&7 of the staged row
    const int sch   = (l & 7) ^ srow8;      // per-lane constant source chunk
    const unsigned short* ag = A  + (size_t)(m0 + w * 32 + srow8) * DM_ + sch * 8;
    const unsigned short* bg = Wt + (size_t)(n0 + w * 32 + srow8) * DM_ + sch * 8;

    const f32x4 fz = {0.f, 0.f, 0.f, 0.f};
    f32x4 acc[4][4];
    #pragma unroll
    for (int i = 0; i < 4; ++i)
        #pragma unroll
        for (int j = 0; j < 4; ++j) acc[i][j] = fz;

    const int rsw = l16 & 7;                // row&7 of this lane's frag rows
    for (int k0 = 0; k0 < DM_; k0 += 64) {
        __syncthreads();
        #pragma unroll
        for (int s = 0; s < 4; ++s) {
            async16(ag + k0 + (size_t)(s * 8) * DM_, &As[(w * 32 + s * 8) * 64]);
            async16(bg + k0 + (size_t)(s * 8) * DM_, &Bs[(w * 32 + s * 8) * 64]);
        }
        __syncthreads();
        #pragma unroll
        for (int c = 0; c < 2; ++c) {
            const int csw = ((c * 4 + quad) ^ rsw) * 8;
            bf16x8 af[4], bfr[4];
            #pragma unroll
            for (int i = 0; i < 4; ++i)
                af[i] = *(const bf16x8*)&As[(wr * 64 + i * 16 + l16) * 64 + csw];
            #pragma unroll
            for (int j = 0; j < 4; ++j)
                bfr[j] = *(const bf16x8*)&Bs[(wc * 64 + j * 16 + l16) * 64 + csw];
            #pragma unroll
            for (int i = 0; i < 4; ++i)
                #pragma unroll
                for (int j = 0; j < 4; ++j)
                    acc[i][j] = MFMA16(af[i], bfr[j], acc[i][j]);
        }
    }

    float bv[4];
    #pragma unroll
    for (int j = 0; j < 4; ++j) bv[j] = bias[n0 + wc * 64 + j * 16 + l16];

    if (mode == 2) {
        float* out = (float*)outp;
        #pragma unroll
        for (int i = 0; i < 4; ++i)
            #pragma unroll
            for (int j = 0; j < 4; ++j) {
                int col = n0 + wc * 64 + j * 16 + l16;
                #pragma unroll
                for (int r = 0; r < 4; ++r) {
                    int row = m0 + wr * 64 + i * 16 + quad * 4 + r;
                    out[(size_t)row * DM_ + col] = acc[i][j][r] + bv[j];
                }
            }
    } else if (mode == 0) {   // [B,H,S,64] bf16
        unsigned short* out = (unsigned short*)outp;
        #pragma unroll
        for (int i = 0; i < 4; ++i)
            #pragma unroll
            for (int j = 0; j < 4; ++j) {
                int col = n0 + wc * 64 + j * 16 + l16;
                int h = col >> 6, d = col & 63;
                #pragma unroll
                for (int r = 0; r < 4; ++r) {
                    int row = m0 + wr * 64 + i * 16 + quad * 4 + r;
                    int bb = row >> 11, ss = row & (S_ - 1);
                    out[(((size_t)bb * H_ + h) * S_ + ss) * HD_ + d] =
                        f2bf(acc[i][j][r] + bv[j]);
                }
            }
    } else {                  // mode 1: [B,H,64,S] bf16, pack 4 consecutive s
        unsigned short* out = (unsigned short*)outp;
        #pragma unroll
        for (int i = 0; i < 4; ++i)
            #pragma unroll
            for (int j = 0; j < 4; ++j) {
                int col = n0 + wc * 64 + j * 16 + l16;
                int h = col >> 6, d = col & 63;
                int row0 = m0 + wr * 64 + i * 16 + quad * 4;
                int bb = row0 >> 11, ss = row0 & (S_ - 1);
                ushort4 o = make_ushort4(f2bf(acc[i][j][0] + bv[j]),
                                         f2bf(acc[i][j][1] + bv[j]),
                                         f2bf(acc[i][j][2] + bv[j]),
                                         f2bf(acc[i][j][3] + bv[j]));
                *(ushort4*)(out + (((size_t)bb * H_ + h) * HD_ + d) * S_ + ss) = o;
            }
    }
}

// fused Q/K/V projection: z picks input/weight/bias/output/mode
__global__ __launch_bounds__(256) void gemm_qkv3(
    const unsigned short* __restrict__ Qc, const unsigned short* __restrict__ Kc,
    const unsigned short* __restrict__ Vc,
    const unsigned short* __restrict__ Wqt, const unsigned short* __restrict__ Wkt,
    const unsigned short* __restrict__ Wvt,
    const float* __restrict__ bq, const float* __restrict__ bk,
    const float* __restrict__ bvp,
    unsigned short* __restrict__ qh, unsigned short* __restrict__ kh,
    unsigned short* __restrict__ vth)
{
    __shared__ unsigned short As[128 * 64];
    __shared__ unsigned short Bs[128 * 64];
    const int z = blockIdx.z;
    const unsigned short* A  = z == 0 ? Qc  : (z == 1 ? Kc  : Vc);
    const unsigned short* Wt = z == 0 ? Wqt : (z == 1 ? Wkt : Wvt);
    const float* bias        = z == 0 ? bq  : (z == 1 ? bk  : bvp);
    void* out                = z == 0 ? (void*)qh : (z == 1 ? (void*)kh : (void*)vth);
    gemm_body(A, Wt, bias, out, z == 2 ? 1 : 0, As, Bs);
}

__global__ __launch_bounds__(256) void gemm_omfma(
    const unsigned short* __restrict__ A, const unsigned short* __restrict__ Wt,
    const float* __restrict__ bias, float* __restrict__ out)
{
    __shared__ unsigned short As[128 * 64];
    __shared__ unsigned short Bs[128 * 64];
    gemm_body(A, Wt, bias, out, 2, As, Bs);
}

// ---------------------------------------------------------------------------
// MFMA flash attention, transposed scores (K.Q^T so each lane owns one q-row's
// scores). No max tracking; mask additive {0,-inf}; l summed in f32.
// K/V/mask software-pipelined: global_load -> VGPR at iter i, ds_write at
// iter i+1 (a full iteration of latency slack; barriers order only LDS).
// ---------------------------------------------------------------------------
__global__ __launch_bounds__(256) void attn_mfma(
    const unsigned short* __restrict__ q,
    const unsigned short* __restrict__ k,
    const unsigned short* __restrict__ vt,
    const int* __restrict__ mask,
    unsigned short* __restrict__ out)
{
    __shared__ unsigned short Qs[128 * 64];
    __shared__ unsigned short Ks[64 * 64];
    __shared__ unsigned short Vs[64 * 64];       // [dv][key]
    __shared__ unsigned short Ps[4][2][16 * 64]; // per wave, per q-group
    __shared__ float msf[64];
    const int t = threadIdx.x;
    const int w = t >> 6, l = t & 63;
    const int quad = l >> 4, l16 = l & 15;
    const int b = blockIdx.z, h = blockIdx.y;
    const int q0 = blockIdx.x * 128;
    const size_t hb = ((size_t)b * H_ + h) * S_;
    const float C_ = 0.18033688011112042f;       // 0.125 * log2(e)
    const float NINF = -__builtin_inff();

    const int srow8 = l >> 3;
    const int sch   = (l & 7) ^ srow8;

    // stage Q once via async16 (swizzled 16B chunks)
    const unsigned short* qg = q + (hb + q0) * HD_;
    #pragma unroll
    for (int s = 0; s < 4; ++s) {
        int r0 = w * 32 + s * 8;
        async16(qg + (size_t)(r0 + srow8) * HD_ + sch * 8, &Qs[r0 * 64]);
    }

    // --- K/V/mask software pipeline ---
    // wave w owns rows [w*16, w*16+16) of K and V tiles; 2 chunks (16B) per lane
    const int prow = w * 16 + (l >> 2);          // K/V row this lane loads
    const int pc0 = l & 3;                       // chunk index, +4 for second
    const unsigned short* kg0 = k + hb * HD_;
    const unsigned short* vg0 = vt + ((size_t)b * H_ + h) * HD_ * S_;
    const unsigned short* kgl = kg0 + (size_t)prow * HD_ + pc0 * 8;
    const unsigned short* vgl = vg0 + (size_t)prow * S_ + pc0 * 8;
    const int* mgl = mask + (size_t)b * S_ + l;
    // swizzled LDS dests
    unsigned short* kdst0 = &Ks[prow * 64 + ((pc0 ^ (prow & 7)) * 8)];
    unsigned short* kdst1 = &Ks[prow * 64 + (((pc0 + 4) ^ (prow & 7)) * 8)];
    unsigned short* vdst0 = &Vs[prow * 64 + ((pc0 ^ (prow & 7)) * 8)];
    unsigned short* vdst1 = &Vs[prow * 64 + (((pc0 + 4) ^ (prow & 7)) * 8)];

    bf16x8 kreg[2], vreg[2];
    int mreg;
    // prologue: prefetch tile 0
    kreg[0] = *(const bf16x8*)(kgl);
    kreg[1] = *(const bf16x8*)(kgl + 32);
    vreg[0] = *(const bf16x8*)(vgl);
    vreg[1] = *(const bf16x8*)(vgl + 32);
    mreg = *mgl;

    __syncthreads();   // Q staged
    bf16x8 qf[2][2];   // [q-group][d-half], B-operand frags (row-major [q][d])
    #pragma unroll
    for (int g = 0; g < 2; ++g)
        #pragma unroll
        for (int c = 0; c < 2; ++c) {
            int row = w * 32 + g * 16 + l16;
            qf[g][c] = *(const bf16x8*)&Qs[row * 64 + (((c * 4 + quad) ^ (row & 7)) * 8)];
        }

    const f32x4 fz = {0.f, 0.f, 0.f, 0.f};
    f32x4 o[2][4];
    float lr[2] = {0.f, 0.f};
    #pragma unroll
    for (int g = 0; g < 2; ++g)
        #pragma unroll
        for (int jv = 0; jv < 4; ++jv) o[g][jv] = fz;

    const int rsw = l16 & 7;

    for (int kt = 0; kt < S_ / 64; ++kt) {
        __syncthreads();                 // prev iter's LDS reads done
        // commit prefetched tile to LDS
        *(bf16x8*)kdst0 = kreg[0];
        *(bf16x8*)kdst1 = kreg[1];
        *(bf16x8*)vdst0 = vreg[0];
        *(bf16x8*)vdst1 = vreg[1];
        msf[l] = mreg ? 0.f : NINF;      // all 4 waves write identical values
        // issue next tile's loads (clamped; full iteration of latency slack)
        {
            int ktn = kt + 1 < S_ / 64 ? kt + 1 : kt;
            const unsigned short* kp = kgl + (size_t)ktn * 64 * HD_;
            const unsigned short* vp = vgl + ktn * 64;
            kreg[0] = *(const bf16x8*)(kp);
            kreg[1] = *(const bf16x8*)(kp + 32);
            vreg[0] = *(const bf16x8*)(vp);
            vreg[1] = *(const bf16x8*)(vp + 32);
            mreg = mgl[ktn * 64];
        }
        __syncthreads();                 // LDS writes visible

        // additive mask; lane covers keys kk*16 + quad*4 + r
        float madd[4][4];
        #pragma unroll
        for (int kk = 0; kk < 4; ++kk) {
            float4 mv = *(const float4*)&msf[kk * 16 + quad * 4];
            madd[kk][0] = mv.x; madd[kk][1] = mv.y;
            madd[kk][2] = mv.z; madd[kk][3] = mv.w;
        }

        // K A-frags (row-major [key][d]) and V B-frags (row-major [dv][key])
        bf16x8 kf[4][2], vfr[4][2];
        #pragma unroll
        for (int kk = 0; kk < 4; ++kk) {
            int row = kk * 16 + l16;
            #pragma unroll
            for (int c = 0; c < 2; ++c)
                kf[kk][c] = *(const bf16x8*)&Ks[row * 64 + (((c * 4 + quad) ^ rsw) * 8)];
        }
        #pragma unroll
        for (int jv = 0; jv < 4; ++jv) {
            int row = jv * 16 + l16;
            #pragma unroll
            for (int c = 0; c < 2; ++c)
                vfr[jv][c] = *(const bf16x8*)&Vs[row * 64 + (((c * 4 + quad) ^ rsw) * 8)];
        }

        #pragma unroll
        for (int g = 0; g < 2; ++g) {
            // scores: D[key = kk*16 + quad*4 + r][q = g*16 + l16]
            f32x4 sc[4];
            #pragma unroll
            for (int kk = 0; kk < 4; ++kk) sc[kk] = fz;
            #pragma unroll
            for (int kk = 0; kk < 4; ++kk) {
                sc[kk] = MFMA16(kf[kk][0], qf[g][0], sc[kk]);
                sc[kk] = MFMA16(kf[kk][1], qf[g][1], sc[kk]);
            }
            // p = exp2(s*C + madd); truncate-pack to bf16; l from f32 values
            unsigned short* Pg = &Ps[w][g][0];
            float lacc = 0.f;
            #pragma unroll
            for (int kk = 0; kk < 4; ++kk) {
                int kb = (kk * 2 + (quad >> 1)) ^ rsw;
                #pragma unroll
                for (int rp = 0; rp < 2; ++rp) {
                    float p0 = __builtin_amdgcn_exp2f(
                        fmaf(sc[kk][rp * 2 + 0], C_, madd[kk][rp * 2 + 0]));
                    float p1 = __builtin_amdgcn_exp2f(
                        fmaf(sc[kk][rp * 2 + 1], C_, madd[kk][rp * 2 + 1]));
                    unsigned int pk = __builtin_amdgcn_perm(f2u(p1), f2u(p0), 0x07060302u);
                    lacc += p0 + p1;
                    *(unsigned int*)&Pg[l16 * 64 + kb * 8 + (quad & 1) * 4 + rp * 2] = pk;
                }
            }
            lr[g] += lacc;
            // PV: A = P^[q=l16][key], B = V rows [dv][key]; O D[q=quad*4+r][dv=l16]
            bf16x8 pa0 = *(const bf16x8*)&Pg[l16 * 64 + ((quad ^ rsw) * 8)];
            bf16x8 pa1 = *(const bf16x8*)&Pg[l16 * 64 + (((4 + quad) ^ rsw) * 8)];
            #pragma unroll
            for (int jv = 0; jv < 4; ++jv) {
                o[g][jv] = MFMA16(pa0, vfr[jv][0], o[g][jv]);
                o[g][jv] = MFMA16(pa1, vfr[jv][1], o[g][jv]);
            }
        }
    }
    // epilogue: row sums across quads, broadcast inv to O layout, store bf16
    #pragma unroll
    for (int g = 0; g < 2; ++g) {
        float ls = lr[g];
        ls += __shfl_xor(ls, 16);
        ls += __shfl_xor(ls, 32);
        float inv = 1.0f / ls;
        float invr[4];
        #pragma unroll
        for (int r = 0; r < 4; ++r)
            invr[r] = __shfl(inv, (l & 48) | (quad * 4 + r));
        #pragma unroll
        for (int jv = 0; jv < 4; ++jv) {
            int col = h * HD_ + jv * 16 + l16;
            #pragma unroll
            for (int r = 0; r < 4; ++r) {
                int row = q0 + w * 32 + g * 16 + quad * 4 + r;
                out[((size_t)b * S_ + row) * DM_ + col] = f2bf(o[g][jv][r] * invr[r]);
            }
        }
    }
}

extern "C" void kernel_launch(void* const* d_in, const int* in_sizes, int n_in,
                              void* d_out, int out_size, void* d_ws, size_t ws_size,
                              hipStream_t stream) {
    const float* Q    = (const float*)d_in[0];
    const float* K    = (const float*)d_in[1];
    const float* V    = (const float*)d_in[2];
    const int*   mask = (const int*)d_in[3];
    const float* Wq   = (const float*)d_in[4];
    const float* bq   = (const float*)d_in[5];
    const float* Wk   = (const float*)d_in[6];
    const float* bk   = (const float*)d_in[7];
    const float* Wv   = (const float*)d_in[8];
    const float* bv   = (const float*)d_in[9];
    const float* Wo   = (const float*)d_in[10];
    const float* bo   = (const float*)d_in[11];

    char* ws = (char*)d_ws;
    const size_t MB = 1024 * 1024;
    unsigned short* Qc  = (unsigned short*)(ws);            // 16 MB each
    unsigned short* Kc  = (unsigned short*)(ws + 16 * MB);
    unsigned short* Vc  = (unsigned short*)(ws + 32 * MB);
    unsigned short* Wqt = (unsigned short*)(ws + 48 * MB);  // 2 MB each
    unsigned short* Wkt = (unsigned short*)(ws + 50 * MB);
    unsigned short* Wvt = (unsigned short*)(ws + 52 * MB);
    unsigned short* Wot = (unsigned short*)(ws + 54 * MB);
    unsigned short* qh  = (unsigned short*)(ws + 56 * MB);  // [B,H,S,64]
    unsigned short* kh  = (unsigned short*)(ws + 72 * MB);
    unsigned short* vth = (unsigned short*)(ws + 88 * MB);  // [B,H,64,S]
    unsigned short* ao  = (unsigned short*)(ws + 104 * MB); // [B,S,DM]

    cast3_bf16<<<dim3(4096, 1, 3), 256, 0, stream>>>(Q, K, V, Qc, Kc, Vc);
    wcast4_t<<<dim3(16, 16, 4), 256, 0, stream>>>(Wq, Wk, Wv, Wo, Wqt, Wkt, Wvt, Wot);
    gemm_qkv3<<<dim3(DM_ / 128, (B_ * S_) / 128, 3), 256, 0, stream>>>(
        Qc, Kc, Vc, Wqt, Wkt, Wvt, bq, bk, bv, qh, kh, vth);
    attn_mfma<<<dim3(S_ / 128, H_, B_), 256, 0, stream>>>(qh, kh, vth, mask, ao);
    gemm_omfma<<<dim3(DM_ / 128, (B_ * S_) / 128), 256, 0, stream>>>(ao, Wot, bo, (float*)d_out);
}